// Round 4
// baseline (191.803 us; speedup 1.0000x reference)
//
#include <hip/hip_runtime.h>

// Problem constants (from reference):
//   x: (B=16, N_CH=1024, T=2048) fp32
//   W: (M=128, C=8) fp32
//   out0: Ax (16, 128, 2048) fp32   = 4,194,304 elems
//   out1: A_full (128, 1024) fp32   =   131,072 elems
#define B_SZ   16
#define N_CH   1024
#define T_SZ   2048
#define C_BLK  8
#define M_OUT  128

#define T4        (T_SZ / 4)            // 512 float4 per (b,m) row
#define AX_BLOCKS ((B_SZ * M_OUT * T4) / 256)   // 4096 blocks for Ax
#define AF_VEC4   ((M_OUT * N_CH) / 4)          // 32768 float4 for A_full
#define AF_BLOCKS (AF_VEC4 / 256)               // 128 blocks for A_full

// Native clang vector type — required by __builtin_nontemporal_store
// (HIP_vector_type float4 is a struct and is rejected).
typedef float vfloat4 __attribute__((ext_vector_type(4)));

// Fused kernel: blocks [0, AX_BLOCKS) compute Ax; blocks [AX_BLOCKS, +AF_BLOCKS)
// materialize A_full. Branch is block-uniform (no divergence).
//
// Round-4 change: x loads are PLAIN (cache-allocating) — the harness's x
// restore copy runs immediately before this kernel each iteration and x
// (128 MiB) fits in the 256 MiB Infinity Cache, so allocating reads can hit
// L3 at >HBM bandwidth. nt on loads was bypassing those hits. Stores stay
// nontemporal (outputs are never re-read in the timed path).
//
// Ax[b,m,t] = sum_c x[b, m*8+c, t] * W[m,c]
//   One thread per float4 along t; a block covers 256 consecutive float4s of
//   one (b,m) row (2 blocks/row), so m is block-uniform and the 8 W loads are
//   scalar-cached broadcasts. Each lane: 8 coalesced vec4 loads (1 KiB/wave
//   each), 8 packed FMAs, 1 nt vec4 store.
//
// A_full[r, col] = (col>>3 == r) ? W[r, col&7] : 0
__global__ __launch_bounds__(256)
void fused_kernel(const float* __restrict__ x,
                  const float* __restrict__ W,
                  float* __restrict__ ax_out,
                  float* __restrict__ afull_out) {
    const int bid = blockIdx.x;
    if (bid < AX_BLOCKS) {
        const int gid = bid * 256 + threadIdx.x;      // float4 index into Ax
        const int t4  = gid & (T4 - 1);               // [0, 512)
        const int row = gid >> 9;                     // b*M + m
        const int m   = row & (M_OUT - 1);
        // base channel: b*N_CH + m*C_BLK == row*C_BLK  (N_CH = M*C)
        const vfloat4* xp = reinterpret_cast<const vfloat4*>(x)
                          + (size_t)row * C_BLK * T4 + t4;

        vfloat4 acc = (vfloat4)(0.f);
#pragma unroll
        for (int c = 0; c < C_BLK; ++c) {
            const float   w  = W[m * C_BLK + c];
            const vfloat4 xv = xp[(size_t)c * T4];    // plain, cache-allocating
            acc += w * xv;   // vector FMA (compiler fuses mul+add into v_fma)
        }
        __builtin_nontemporal_store(acc, reinterpret_cast<vfloat4*>(ax_out) + gid);
    } else {
        const int i4   = (bid - AX_BLOCKS) * 256 + threadIdx.x;  // [0, 32768)
        const int r    = i4 >> 8;            // row (256 float4 per row)
        const int col4 = i4 & 255;           // float4 index within row
        const int blk  = col4 >> 1;          // 8-col block this float4 lies in
        vfloat4 v = (vfloat4)(0.f);
        if (blk == r) {
            const vfloat4* wrow = reinterpret_cast<const vfloat4*>(W + r * C_BLK);
            v = wrow[col4 & 1];              // first or second half of W[r,:]
        }
        __builtin_nontemporal_store(v, reinterpret_cast<vfloat4*>(afull_out) + i4);
    }
}

extern "C" void kernel_launch(void* const* d_in, const int* in_sizes, int n_in,
                              void* d_out, int out_size, void* d_ws, size_t ws_size,
                              hipStream_t stream) {
    const float* x = (const float*)d_in[0];
    const float* W = (const float*)d_in[1];
    float* out = (float*)d_out;

    float* ax_out    = out;                               // 4,194,304 floats
    float* afull_out = out + (size_t)B_SZ * M_OUT * T_SZ; // next 131,072

    fused_kernel<<<AX_BLOCKS + AF_BLOCKS, 256, 0, stream>>>(x, W, ax_out, afull_out);
}

// Round 5
// 183.224 us; speedup vs baseline: 1.0468x; 1.0468x over previous
//
#include <hip/hip_runtime.h>

// Problem constants (from reference):
//   x: (B=16, N_CH=1024, T=2048) fp32
//   W: (M=128, C=8) fp32
//   out0: Ax (16, 128, 2048) fp32   = 4,194,304 elems
//   out1: A_full (128, 1024) fp32   =   131,072 elems
#define B_SZ   16
#define N_CH   1024
#define T_SZ   2048
#define C_BLK  8
#define M_OUT  128

#define T4        (T_SZ / 4)            // 512 float4 per (b,m) row
#define AX_BLOCKS (B_SZ * M_OUT)        // one block per (b,m) row = 2048
#define AF_VEC4   ((M_OUT * N_CH) / 4)  // 32768 float4 for A_full
#define AF_BLOCKS (AF_VEC4 / 256)       // 128 blocks for A_full

// Native clang vector type — required by __builtin_nontemporal_load/store
// (HIP_vector_type float4 is a struct and is rejected).
typedef float vfloat4 __attribute__((ext_vector_type(4)));

// Round-5 config: nt loads RESTORED (round-4 showed removing them regresses
// 184->192 us: the 512 MiB d_ws poison fill between x-restore and this kernel
// sweeps L3, so x reads always miss — nt avoids wasting allocate BW).
// New: one block per (b,m) row, 2 float4 per thread -> 16 independent nt
// loads in flight per lane, 64 KiB contiguous footprint per block, address
// math amortized.
//
// Ax[b,m,t] = sum_c x[b, m*8+c, t] * W[m,c]
// A_full[r, col] = (col>>3 == r) ? W[r, col&7] : 0
__global__ __launch_bounds__(256)
void fused_kernel(const float* __restrict__ x,
                  const float* __restrict__ W,
                  float* __restrict__ ax_out,
                  float* __restrict__ afull_out) {
    const int bid = blockIdx.x;
    if (bid < AX_BLOCKS) {
        const int row = bid;                          // b*M + m
        const int m   = row & (M_OUT - 1);
        const int t4  = threadIdx.x;                  // [0,256); second elem at +256
        // base channel: b*N_CH + m*C_BLK == row*C_BLK  (N_CH = M*C)
        const vfloat4* xp = reinterpret_cast<const vfloat4*>(x)
                          + (size_t)row * C_BLK * T4 + t4;

        vfloat4 acc0 = (vfloat4)(0.f);
        vfloat4 acc1 = (vfloat4)(0.f);
#pragma unroll
        for (int c = 0; c < C_BLK; ++c) {
            const float   w   = W[m * C_BLK + c];
            const vfloat4 xv0 = __builtin_nontemporal_load(xp + (size_t)c * T4);
            const vfloat4 xv1 = __builtin_nontemporal_load(xp + (size_t)c * T4 + 256);
            acc0 += w * xv0;
            acc1 += w * xv1;
        }
        vfloat4* op = reinterpret_cast<vfloat4*>(ax_out) + (size_t)row * T4 + t4;
        __builtin_nontemporal_store(acc0, op);
        __builtin_nontemporal_store(acc1, op + 256);
    } else {
        const int i4   = (bid - AX_BLOCKS) * 256 + threadIdx.x;  // [0, 32768)
        const int r    = i4 >> 8;            // row (256 float4 per row)
        const int col4 = i4 & 255;           // float4 index within row
        const int blk  = col4 >> 1;          // 8-col block this float4 lies in
        vfloat4 v = (vfloat4)(0.f);
        if (blk == r) {
            const vfloat4* wrow = reinterpret_cast<const vfloat4*>(W + r * C_BLK);
            v = wrow[col4 & 1];              // first or second half of W[r,:]
        }
        __builtin_nontemporal_store(v, reinterpret_cast<vfloat4*>(afull_out) + i4);
    }
}

extern "C" void kernel_launch(void* const* d_in, const int* in_sizes, int n_in,
                              void* d_out, int out_size, void* d_ws, size_t ws_size,
                              hipStream_t stream) {
    const float* x = (const float*)d_in[0];
    const float* W = (const float*)d_in[1];
    float* out = (float*)d_out;

    float* ax_out    = out;                               // 4,194,304 floats
    float* afull_out = out + (size_t)B_SZ * M_OUT * T_SZ; // next 131,072

    fused_kernel<<<AX_BLOCKS + AF_BLOCKS, 256, 0, stream>>>(x, W, ax_out, afull_out);
}